// Round 13
// baseline (1062.636 us; speedup 1.0000x reference)
//
#include <hip/hip_runtime.h>
#include <cstdint>
#include <cstddef>

// ---------------------------------------------------------------------------
// Submanifold sparse conv net, MFMA bf16 implicit-GEMM.
// Round 13: s-outer LDS staging — stage ALL 27 taps of one CIN-slice (27*CT KB)
// per barrier pair, then a barrier-FREE 27-tap inner loop (straight-line code,
// compiler pipelines gathers/ds_reads/MFMAs across taps). Barriers 27 -> 2*NS.
// Swizzled GY cout-slices. Deep levels fp32 chain (round 10).
// ---------------------------------------------------------------------------

typedef __attribute__((ext_vector_type(8))) short short8v;
typedef __attribute__((ext_vector_type(4))) float f32x4;

static inline int cdiv_h(int a, int b) { return (a + b - 1) / b; }

__device__ inline unsigned short f2bf(float f) {
    unsigned int u = __builtin_bit_cast(unsigned int, f);
    u += 0x7FFFu + ((u >> 16) & 1u);
    return (unsigned short)(u >> 16);
}
__device__ inline float bf2f(unsigned short h) {
    unsigned int u = ((unsigned int)h) << 16;
    return __builtin_bit_cast(float, u);
}

// global -> LDS async copy, 16B per lane (wave-uniform LDS base + lane*16).
__device__ inline void gload_lds16(const void* g, void* l) {
    auto gp = (const __attribute__((address_space(1))) unsigned int*)(uintptr_t)g;
    auto lp = (__attribute__((address_space(3))) unsigned int*)(uintptr_t)l;
    __builtin_amdgcn_global_load_lds(gp, lp, 16, 0, 0);
}

// bijective XCD swizzle (m204)
__device__ inline int xcd_swz(int bid, int nwg) {
    int q = nwg >> 3, r = nwg & 7;
    int x = bid & 7, idx = bid >> 3;
    return (x < r ? x * (q + 1) : r * (q + 1) + (x - r) * q) + idx;
}

__global__ void set_count_k(int* counts, int n) { counts[0] = n; }

__global__ void scatter_grid_k(const int* __restrict__ coords, const int* __restrict__ cnt,
                               int* __restrict__ grid, int S)
{
    int i = blockIdx.x * blockDim.x + threadIdx.x;
    if (i >= cnt[0]) return;
    int z = coords[i * 4 + 1], y = coords[i * 4 + 2], x = coords[i * 4 + 3];
    grid[(z * S + y) * S + x] = i;
}

// pairs_t[row][32]: taps 0..26, pad 27..31 = -1. int4-aligned per row.
__global__ void build_pairs_k(const int* __restrict__ coords, const int* __restrict__ cnt,
                              const int* __restrict__ grid, int* __restrict__ pairs_t, int S)
{
    int i = blockIdx.x * blockDim.x + threadIdx.x;
    if (i >= cnt[0]) return;
    int z = coords[i * 4 + 1], y = coords[i * 4 + 2], x = coords[i * 4 + 3];
    int4* dst = reinterpret_cast<int4*>(pairs_t + (size_t)i * 32);
#pragma unroll
    for (int g = 0; g < 7; ++g) {
        int4 q;
#pragma unroll
        for (int j = 0; j < 4; ++j) {
            int k = g * 4 + j;
            int v = -1;
            if (k < 27) {
                int nz = z + k / 9 - 1;
                int ny = y + (k / 3) % 3 - 1;
                int nx = x + k % 3 - 1;
                if (nz >= 0 && nz < S && ny >= 0 && ny < S && nx >= 0 && nx < S)
                    v = grid[(nz * S + ny) * S + nx];
            }
            ((int*)&q)[j] = v;
        }
        dst[g] = q;
    }
}

// ---- fused weight pre-pack: fp32 [27][CIN][COUT] -> bf16 fragment tiles -----
struct PackArgs {
    const float* src[13];
    unsigned short* dst[13];
    int cin[13];
    int cout[13];
    int tileStart[14];
};

__global__ __launch_bounds__(256) void pack_all_k(PackArgs pa)
{
    int g = blockIdx.x * 4 + ((int)threadIdx.x >> 6);
    int lane = (int)threadIdx.x & 63;
    if (g >= pa.tileStart[13]) return;
    int li = 0;
    while (li < 12 && g >= pa.tileStart[li + 1]) ++li;
    int tile = g - pa.tileStart[li];
    int CIN = pa.cin[li], COUT = pa.cout[li];
    int NS = CIN >> 5, NT = COUT >> 4;
    int t = tile % NT;
    int s = (tile / NT) % NS;
    int k = tile / (NT * NS);
    int kabs = s * 32 + (lane >> 4) * 8;
    int c = t * 16 + (lane & 15);
    const float* src = pa.src[li] + ((size_t)(k * CIN + kabs)) * COUT + c;
    unsigned short* dst = pa.dst[li] + (size_t)tile * 512 + lane * 8;
#pragma unroll
    for (int j = 0; j < 8; ++j) dst[j] = f2bf(src[(size_t)j * COUT]);
}

// ---- first layer (CIN=3) fp32 vector, writes bf16 ---------------------------
__global__ __launch_bounds__(256) void conv0_k(
    const float* __restrict__ fin, const float* __restrict__ W,
    const int* __restrict__ pairs_t, const int* __restrict__ cnt,
    unsigned short* __restrict__ fout)
{
    const int row = blockIdx.x * 16 + ((int)threadIdx.x >> 4);
    const int cg = ((int)threadIdx.x & 15) * 4;
    if (row >= cnt[0]) return;
    float a0 = 0, a1 = 0, a2 = 0, a3 = 0;
    for (int k = 0; k < 27; ++k) {
        int nb = pairs_t[(size_t)row * 32 + k];
        if (nb < 0) continue;
        const float* fr = fin + (size_t)nb * 3;
        const float* wk = W + (size_t)k * 3 * 64 + cg;
#pragma unroll
        for (int ci = 0; ci < 3; ++ci) {
            float f = fr[ci];
            float4 w = *reinterpret_cast<const float4*>(wk + ci * 64);
            a0 += f * w.x; a1 += f * w.y; a2 += f * w.z; a3 += f * w.w;
        }
    }
    size_t o = (size_t)row * 64 + cg;
    fout[o] = f2bf(a0); fout[o + 1] = f2bf(a1);
    fout[o + 2] = f2bf(a2); fout[o + 3] = f2bf(a3);
}

// ---- MFMA conv, s-outer LDS staging (levels 0-2) -----------------------------
// LDS holds ALL 27 taps x CT cout-tiles of ONE CIN-slice s (27*CT KB, single
// buffer). Per s: barrier, stage, barrier, then 27-tap loop with NO syncs.
template <int CIN, int COUT, int RT, int CT, int GY, bool OUTF32>
__global__ __launch_bounds__(256) void conv_sls_k(
    const unsigned short* __restrict__ fin, const unsigned short* __restrict__ Wp,
    const int* __restrict__ pairs_t, const int* __restrict__ cnt,
    void* __restrict__ fout)
{
    constexpr int NS = CIN / 32, NT = COUT / 16;
    constexpr int NCH = 27 * CT;                 // 1KB chunks staged per slice
    __shared__ unsigned short sB[NCH * 512];     // <= 54KB (CT=2)

    const int lane = (int)threadIdx.x & 63;
    const int wave = (int)threadIdx.x >> 6;
    const int l15 = lane & 15, lhi = lane >> 4;
    const int M = cnt[0];

    const int lid = xcd_swz((int)blockIdx.x, (int)gridDim.x);
    const int rowBlock = lid / GY;
    const int ct0 = (lid % GY) * CT;
    const int rowBase = (rowBlock * 4 + wave) * (RT * 16);

    const unsigned short* __restrict__ finL = fin + (size_t)lhi * 8;
    const unsigned short* __restrict__ WpL  = Wp + (size_t)lane * 8;

    f32x4 acc[RT][CT];
#pragma unroll
    for (int a = 0; a < RT; ++a)
#pragma unroll
        for (int b = 0; b < CT; ++b) acc[a][b] = (f32x4){0.f, 0.f, 0.f, 0.f};

    int  rowC[RT];
    bool rOK[RT];
#pragma unroll
    for (int rt = 0; rt < RT; ++rt) {
        int r = rowBase + rt * 16 + l15;
        rOK[rt]  = r < M;
        rowC[rt] = rOK[rt] ? r : 0;
    }

    for (int s = 0; s < NS; ++s) {
        if (s) __syncthreads();  // all waves done reading sB for slice s-1
        // stage slice s: all 27 taps x CT cout-tiles (wave-strided chunks)
#pragma unroll
        for (int idx = wave; idx < NCH; idx += 4) {
            int k = idx / CT, tt = idx % CT;
            gload_lds16(WpL + ((size_t)(k * NS + s) * NT + ct0 + tt) * 512,
                        &sB[idx * 512]);
        }
        __syncthreads();  // stage complete & visible (vmcnt drain + barrier)

        // ---- 27-tap loop: NO barriers, straight-line, compiler pipelines ----
#pragma unroll
        for (int kg = 0; kg < 7; ++kg) {
            int4 nb4[RT];
#pragma unroll
            for (int rt = 0; rt < RT; ++rt) {
                nb4[rt] = rOK[rt]
                    ? *reinterpret_cast<const int4*>(pairs_t + (size_t)rowC[rt] * 32 + kg * 4)
                    : make_int4(-1, -1, -1, -1);
            }
#pragma unroll
            for (int j = 0; j < 4; ++j) {
                const int k = kg * 4 + j;
                if (k >= 27) continue;  // constant-folds
                int nb[RT];
#pragma unroll
                for (int rt = 0; rt < RT; ++rt)
                    nb[rt] = (j == 0) ? nb4[rt].x : (j == 1) ? nb4[rt].y
                           : (j == 2) ? nb4[rt].z : nb4[rt].w;

                short8v afr[RT];
#pragma unroll
                for (int rt = 0; rt < RT; ++rt) {
                    afr[rt] = (short8v){};
                    if (nb[rt] >= 0)
                        afr[rt] = *reinterpret_cast<const short8v*>(
                            finL + (size_t)nb[rt] * CIN + s * 32);
                }
                short8v bb[CT];
#pragma unroll
                for (int t = 0; t < CT; ++t)
                    bb[t] = *reinterpret_cast<const short8v*>(
                        &sB[(k * CT + t) * 512 + lane * 8]);
#pragma unroll
                for (int rt = 0; rt < RT; ++rt) {
                    if (!__any(nb[rt] >= 0)) continue;
#pragma unroll
                    for (int t = 0; t < CT; ++t)
                        acc[rt][t] = __builtin_amdgcn_mfma_f32_16x16x32_bf16(
                            afr[rt], bb[t], acc[rt][t], 0, 0, 0);
                }
            }
        }
    }

    // epilogue: C layout col = lane&15, row = (lane>>4)*4 + reg
#pragma unroll
    for (int rt = 0; rt < RT; ++rt) {
#pragma unroll
        for (int j = 0; j < 4; ++j) {
            int r = rowBase + rt * 16 + lhi * 4 + j;
            if (r >= M) continue;
#pragma unroll
            for (int t = 0; t < CT; ++t) {
                int c = (ct0 + t) * 16 + l15;
                if constexpr (OUTF32)
                    ((float*)fout)[(size_t)r * COUT + c] = acc[rt][t][j];
                else
                    ((unsigned short*)fout)[(size_t)r * COUT + c] = f2bf(acc[rt][t][j]);
            }
        }
    }
}

// ---- deep-level conv (levels 3-6): 1-wave blocks, tap/cout split, fp32 atomics
template <int CIN, int COUT, int CTD, int TG, bool INF32>
__global__ __launch_bounds__(64) void conv_deep_k(
    const void* __restrict__ fin, const unsigned short* __restrict__ Wp,
    const int* __restrict__ pairs_t, const int* __restrict__ cnt,
    float* __restrict__ fout)
{
    constexpr int NS = CIN / 32, NT = COUT / 16;
    const int lane = (int)threadIdx.x;
    const int l15 = lane & 15, lhi = lane >> 4;
    const int M = cnt[0];
    if ((int)blockIdx.x * 16 >= M) return;
    const int row = blockIdx.x * 16 + l15;
    const int ct0 = blockIdx.y * CTD;
    const int k0 = blockIdx.z * TG;

    f32x4 acc[CTD];
#pragma unroll
    for (int t = 0; t < CTD; ++t) acc[t] = (f32x4){0.f, 0.f, 0.f, 0.f};

    bool anyTap = false;
#pragma unroll
    for (int kk = 0; kk < TG; ++kk) {
        const int k = k0 + kk;
        int nb = (row < M) ? pairs_t[(size_t)row * 32 + k] : -1;
        if (!__any(nb >= 0)) continue;
        anyTap = true;
        const unsigned short* wk = Wp + (size_t)k * NS * NT * 512 + (size_t)lane * 8;
#pragma unroll
        for (int s = 0; s < NS; ++s) {
            short8v a = (short8v){};
            if (nb >= 0) {
                if constexpr (INF32) {
                    const float* fr = (const float*)fin + (size_t)nb * CIN + s * 32 + lhi * 8;
#pragma unroll
                    for (int j = 0; j < 8; ++j)
                        ((unsigned short*)&a)[j] = f2bf(fr[j]);
                } else {
                    a = *reinterpret_cast<const short8v*>(
                        (const unsigned short*)fin + (size_t)nb * CIN + s * 32 + lhi * 8);
                }
            }
#pragma unroll
            for (int t = 0; t < CTD; ++t) {
                short8v b = *reinterpret_cast<const short8v*>(
                    wk + ((size_t)s * NT + ct0 + t) * 512);
                acc[t] = __builtin_amdgcn_mfma_f32_16x16x32_bf16(a, b, acc[t], 0, 0, 0);
            }
        }
    }
    if (!anyTap) return;

#pragma unroll
    for (int t = 0; t < CTD; ++t)
#pragma unroll
        for (int j = 0; j < 4; ++j) {
            int r = blockIdx.x * 16 + lhi * 4 + j;
            if (r < M)
                atomicAdd(&fout[(size_t)r * COUT + (ct0 + t) * 16 + l15], acc[t][j]);
        }
}

// ---- pooling structure: multi-block scan ------------------------------------
__global__ void mark_occ_k(const int* __restrict__ coords, const int* __restrict__ cnt,
                           int* __restrict__ occ, int Sh)
{
    int i = blockIdx.x * blockDim.x + threadIdx.x;
    if (i >= cnt[0]) return;
    int z = coords[i * 4 + 1] >> 1, y = coords[i * 4 + 2] >> 1, x = coords[i * 4 + 3] >> 1;
    occ[(z * Sh + y) * Sh + x] = 1;
}

__global__ __launch_bounds__(256) void scan_sum_k(const int* __restrict__ occ, int P,
                                                  int* __restrict__ bsum)
{
    int base = blockIdx.x * 4096 + (int)threadIdx.x * 16;
    int s = 0;
#pragma unroll
    for (int j = 0; j < 16; ++j) { int i = base + j; s += (i < P) ? occ[i] : 0; }
    for (int off = 1; off < 64; off <<= 1) s += __shfl_xor(s, off);
    __shared__ int ws[4];
    if ((threadIdx.x & 63) == 0) ws[threadIdx.x >> 6] = s;
    __syncthreads();
    if (threadIdx.x == 0) bsum[blockIdx.x] = ws[0] + ws[1] + ws[2] + ws[3];
}

__global__ void scan_offsets_k(const int* __restrict__ bsum, int nb,
                               int* __restrict__ boff, int* __restrict__ cntOut)
{
    int lane = threadIdx.x;  // 64 threads, nb <= 64
    int v = (lane < nb) ? bsum[lane] : 0;
    int incl = v;
    for (int off = 1; off < 64; off <<= 1) {
        int t = __shfl_up(incl, off);
        if (lane >= off) incl += t;
    }
    if (lane < nb) boff[lane] = incl - v;
    if (lane == 63) cntOut[0] = incl;
}

__global__ __launch_bounds__(256) void scan_emit_k(const int* __restrict__ occ, int P,
                                                   const int* __restrict__ boff,
                                                   int* __restrict__ newcoords, int Sh)
{
    __shared__ int ws[4];
    int tid = threadIdx.x;
    int base = blockIdx.x * 4096 + tid * 16;
    int v[16];
    int s = 0;
#pragma unroll
    for (int j = 0; j < 16; ++j) { int i = base + j; v[j] = (i < P) ? occ[i] : 0; s += v[j]; }
    int mysum = s;
    int incl = s;
    for (int off = 1; off < 64; off <<= 1) {
        int t = __shfl_up(incl, off);
        if ((tid & 63) >= off) incl += t;
    }
    if ((tid & 63) == 63) ws[tid >> 6] = incl;
    __syncthreads();
    int waveOff = 0;
    for (int w = 0; w < (tid >> 6); ++w) waveOff += ws[w];
    int r = boff[blockIdx.x] + waveOff + incl - mysum;
    const int SS = Sh * Sh;
#pragma unroll
    for (int j = 0; j < 16; ++j) {
        if (v[j]) {
            int c = base + j;
            newcoords[r * 4 + 0] = 0;
            newcoords[r * 4 + 1] = c / SS;
            newcoords[r * 4 + 2] = (c % SS) / Sh;
            newcoords[r * 4 + 3] = c % Sh;
            ++r;
        }
    }
}

// max over (up to) 8 children; INF32 selects fp32 vs bf16 input features.
template <bool INF32>
__global__ void pool_max_k(const void* __restrict__ fin, const int* __restrict__ gridPrev,
                           const int* __restrict__ newcoords, const int* __restrict__ cnt,
                           unsigned short* __restrict__ fout, int C, int Sprev)
{
    int idx = blockIdx.x * blockDim.x + threadIdx.x;
    int r = idx / C, c = idx % C;
    if (r >= cnt[0]) return;
    int z2 = newcoords[r * 4 + 1] * 2;
    int y2 = newcoords[r * 4 + 2] * 2;
    int x2 = newcoords[r * 4 + 3] * 2;
    float best = -3.4e38f;
    unsigned short bb = 0;
#pragma unroll
    for (int d = 0; d < 8; ++d) {
        int z = z2 + (d >> 2), y = y2 + ((d >> 1) & 1), x = x2 + (d & 1);
        int j = gridPrev[(z * Sprev + y) * Sprev + x];
        if (j >= 0) {
            if constexpr (INF32) {
                float f = ((const float*)fin)[(size_t)j * C + c];
                if (f > best) best = f;
            } else {
                unsigned short u = ((const unsigned short*)fin)[(size_t)j * C + c];
                float f = bf2f(u);
                if (f > best) { best = f; bb = u; }
            }
        }
    }
    fout[(size_t)r * C + c] = INF32 ? f2bf(best) : bb;
}

// ---------------------------------------------------------------------------

template <int CIN, int COUT, int RT, int CT, int GY, bool OUTF32>
static void launch_cs(const unsigned short* fin, const unsigned short* Wp,
                      const int* pairs_t, const int* cnt, void* fout,
                      int bound, hipStream_t stream)
{
    constexpr int NT = COUT / 16;
    static_assert(CIN % 32 == 0 && COUT % 16 == 0 && CT * GY == NT, "shape");
    static_assert(27 * CT * 1024 <= 65536, "LDS");
    dim3 g(cdiv_h(bound, RT * 64) * GY);
    conv_sls_k<CIN, COUT, RT, CT, GY, OUTF32><<<g, 256, 0, stream>>>(fin, Wp, pairs_t,
                                                                     cnt, fout);
}

template <int CIN, int COUT, int CTD, int TG, bool INF32>
static void launch_deep(const void* fin, const unsigned short* Wp,
                        const int* pairs_t, const int* cnt, float* acc,
                        int bound, hipStream_t stream)
{
    constexpr int NT = COUT / 16;
    static_assert(NT % CTD == 0 && 27 % TG == 0, "shape");
    dim3 g(cdiv_h(bound, 16), NT / CTD, 27 / TG);
    conv_deep_k<CIN, COUT, CTD, TG, INF32><<<g, 64, 0, stream>>>(fin, Wp, pairs_t, cnt, acc);
}

extern "C" void kernel_launch(void* const* d_in, const int* in_sizes, int n_in,
                              void* d_out, int out_size, void* d_ws, size_t ws_size,
                              hipStream_t stream)
{
    const float* feats0 = (const float*)d_in[0];
    const int*   coors  = (const int*)d_in[1];
    const float* w[14];
    for (int i = 0; i < 14; ++i) w[i] = (const float*)d_in[3 + i];
    float* out = (float*)d_out;
    const int N = in_sizes[0] / 3;

    // ---- workspace carve-up ----
    char* p = (char*)d_ws;
    int* grid   = (int*)p; p += (size_t)128 * 128 * 128 * 4;  // 8 MB
    int* occ    = (int*)p; p += (size_t)64 * 64 * 64 * 4;     // 1 MB
    int* counts = (int*)p; p += 256;
    int* bsum   = (int*)p; p += 256;
    int* boff   = (int*)p; p += 256;
    int* pairs_t = (int*)p; p += (size_t)N * 32 * 4;          // [row][32]
    int* coordsA = (int*)p; p += (size_t)N * 16;
    int* coordsB = (int*)p; p += (size_t)N * 16;
    unsigned short* featA = (unsigned short*)p; p += (size_t)N * 96 * 2;
    unsigned short* featB = (unsigned short*)p; p += (size_t)N * 96 * 2;
    float* scrA = (float*)p; p += (size_t)4096 * 192 * 4;     // deep fp32 chain
    float* scrB = (float*)p; p += (size_t)4096 * 192 * 4;
    unsigned short* wpBase = (unsigned short*)p;

    static const int CH[14][2] = {{3,64},{64,64},{64,96},{96,96},{96,128},{128,128},
                                  {128,160},{160,160},{160,192},{192,192},{192,224},
                                  {224,224},{224,256},{256,256}};
    unsigned short* wp[14];
    PackArgs pa;
    {
        size_t off = 0;
        int ts = 0;
        for (int i = 1; i < 14; ++i) {
            wp[i] = wpBase + off;
            off += (size_t)27 * CH[i][0] * CH[i][1];
            pa.src[i - 1] = w[i];
            pa.dst[i - 1] = wp[i];
            pa.cin[i - 1] = CH[i][0];
            pa.cout[i - 1] = CH[i][1];
            pa.tileStart[i - 1] = ts;
            ts += 27 * (CH[i][0] / 32) * (CH[i][1] / 16);
        }
        pa.tileStart[13] = ts;
    }

    int bounds[7];
    for (int l = 0; l < 7; ++l) {
        int S = 128 >> l, c = S * S * S;
        bounds[l] = N < c ? N : c;
    }

    set_count_k<<<1, 1, 0, stream>>>(counts, N);
    hipMemsetAsync(d_out, 0, (size_t)out_size * 4, stream);
    pack_all_k<<<cdiv_h(pa.tileStart[13], 4), 256, 0, stream>>>(pa);

    auto build_level = [&](const int* coordsL, int lvl) {
        int S = 128 >> lvl;
        hipMemsetAsync(grid, 0xFF, (size_t)S * S * S * 4, stream);
        int blocks = cdiv_h(bounds[lvl], 256);
        scatter_grid_k<<<blocks, 256, 0, stream>>>(coordsL, counts + lvl, grid, S);
        build_pairs_k<<<blocks, 256, 0, stream>>>(coordsL, counts + lvl, grid, pairs_t, S);
    };

    auto do_pool = [&](const int* coordsL, int lvl, const void* fin, bool inF32,
                       unsigned short* fout, int C, int* coordsOut) {
        int S = 128 >> lvl, Sh = S / 2, P = Sh * Sh * Sh;
        hipMemsetAsync(occ, 0, (size_t)P * 4, stream);
        mark_occ_k<<<cdiv_h(bounds[lvl], 256), 256, 0, stream>>>(coordsL, counts + lvl, occ, Sh);
        int nb = cdiv_h(P, 4096);
        scan_sum_k<<<nb, 256, 0, stream>>>(occ, P, bsum);
        scan_offsets_k<<<1, 64, 0, stream>>>(bsum, nb, boff, counts + lvl + 1);
        scan_emit_k<<<nb, 256, 0, stream>>>(occ, P, boff, coordsOut, Sh);
        int total = bounds[lvl + 1] * C;
        if (inF32)
            pool_max_k<true><<<cdiv_h(total, 256), 256, 0, stream>>>(
                fin, grid, coordsOut, counts + lvl + 1, fout, C, S);
        else
            pool_max_k<false><<<cdiv_h(total, 256), 256, 0, stream>>>(
                fin, grid, coordsOut, counts + lvl + 1, fout, C, S);
    };

    // ---- level 0 ----
    build_level(coors, 0);
    conv0_k<<<cdiv_h(bounds[0], 16), 256, 0, stream>>>(feats0, w[0], pairs_t, counts + 0, featA);
    launch_cs<64, 64, 2, 2, 2, false>(featA, wp[1], pairs_t, counts + 0, featB, bounds[0], stream);
    do_pool(coors, 0, featB, false, featA, 64, coordsA);
    // ---- level 1 ----
    build_level(coordsA, 1);
    launch_cs<64, 96, 2, 2, 3, false>(featA, wp[2], pairs_t, counts + 1, featB, bounds[1], stream);
    launch_cs<96, 96, 2, 2, 3, false>(featB, wp[3], pairs_t, counts + 1, featA, bounds[1], stream);
    do_pool(coordsA, 1, featA, false, featB, 96, coordsB);
    // ---- level 2 ----
    build_level(coordsB, 2);
    launch_cs<96, 128, 2, 2, 4, false>(featB, wp[4], pairs_t, counts + 2, featA, bounds[2], stream);
    launch_cs<128, 128, 2, 2, 4, false>(featA, wp[5], pairs_t, counts + 2, featB, bounds[2], stream);
    do_pool(coordsB, 2, featB, false, featA, 128, coordsA);
    // ---- level 3 (deep, fp32 chain) ----
    build_level(coordsA, 3);
    hipMemsetAsync(scrA, 0, (size_t)bounds[3] * 160 * 4, stream);
    launch_deep<128, 160, 2, 3, false>(featA, wp[6], pairs_t, counts + 3, scrA, bounds[3], stream);
    hipMemsetAsync(scrB, 0, (size_t)bounds[3] * 160 * 4, stream);
    launch_deep<160, 160, 2, 3, true>(scrA, wp[7], pairs_t, counts + 3, scrB, bounds[3], stream);
    do_pool(coordsA, 3, scrB, true, featB, 160, coordsB);
    // ---- level 4 (deep) ----
    build_level(coordsB, 4);
    hipMemsetAsync(scrA, 0, (size_t)bounds[4] * 192 * 4, stream);
    launch_deep<160, 192, 2, 3, false>(featB, wp[8], pairs_t, counts + 4, scrA, bounds[4], stream);
    hipMemsetAsync(scrB, 0, (size_t)bounds[4] * 192 * 4, stream);
    launch_deep<192, 192, 2, 3, true>(scrA, wp[9], pairs_t, counts + 4, scrB, bounds[4], stream);
    do_pool(coordsB, 4, scrB, true, featA, 192, coordsA);
    // ---- level 5 (deep) ----
    build_level(coordsA, 5);
    hipMemsetAsync(scrA, 0, (size_t)bounds[5] * 224 * 4, stream);
    launch_deep<192, 224, 1, 1, false>(featA, wp[10], pairs_t, counts + 5, scrA, bounds[5], stream);
    hipMemsetAsync(scrB, 0, (size_t)bounds[5] * 224 * 4, stream);
    launch_deep<224, 224, 1, 1, true>(scrA, wp[11], pairs_t, counts + 5, scrB, bounds[5], stream);
    do_pool(coordsA, 5, scrB, true, featB, 224, coordsB);
    // ---- level 6 (deep) ----
    build_level(coordsB, 6);
    hipMemsetAsync(scrA, 0, (size_t)bounds[6] * 256 * 4, stream);
    launch_deep<224, 256, 1, 1, false>(featB, wp[12], pairs_t, counts + 6, scrA, bounds[6], stream);
    // final layer: fp32 in, atomicAdd fp32 straight into d_out (zeroed above)
    launch_deep<256, 256, 1, 1, true>(scrA, wp[13], pairs_t, counts + 6, out, bounds[6], stream);
}

// Round 14
// 746.548 us; speedup vs baseline: 1.4234x; 1.4234x over previous
//
#include <hip/hip_runtime.h>
#include <cstdint>
#include <cstddef>

// ---------------------------------------------------------------------------
// Submanifold sparse conv net, MFMA bf16 implicit-GEMM.
// Round 14: consolidation of measured-best pieces.
//  - conv_lds_k (per-tap-barrier LDS-staged B, RT=2) with XCD swizzle;
//    L0 GY1/CT4, L1 GY1/CT6, L2 GY2/CT4   [round 11 conv config]
//  - deep levels 3-6: bf16-in conv_deep_k + fp32 atomic scratch + f32->bf16
//    convert (round 9 chain; fp32 chain's per-fragment f2bf cost reverted),
//    scratch correctly sized (round 9 overflowed it).
// ---------------------------------------------------------------------------

typedef __attribute__((ext_vector_type(8))) short short8v;
typedef __attribute__((ext_vector_type(4))) float f32x4;

static inline int cdiv_h(int a, int b) { return (a + b - 1) / b; }

__device__ inline unsigned short f2bf(float f) {
    unsigned int u = __builtin_bit_cast(unsigned int, f);
    u += 0x7FFFu + ((u >> 16) & 1u);
    return (unsigned short)(u >> 16);
}
__device__ inline float bf2f(unsigned short h) {
    unsigned int u = ((unsigned int)h) << 16;
    return __builtin_bit_cast(float, u);
}

// global -> LDS async copy, 16B per lane (wave-uniform LDS base + lane*16).
__device__ inline void gload_lds16(const void* g, void* l) {
    auto gp = (const __attribute__((address_space(1))) unsigned int*)(uintptr_t)g;
    auto lp = (__attribute__((address_space(3))) unsigned int*)(uintptr_t)l;
    __builtin_amdgcn_global_load_lds(gp, lp, 16, 0, 0);
}

// bijective XCD swizzle (m204)
__device__ inline int xcd_swz(int bid, int nwg) {
    int q = nwg >> 3, r = nwg & 7;
    int x = bid & 7, idx = bid >> 3;
    return (x < r ? x * (q + 1) : r * (q + 1) + (x - r) * q) + idx;
}

__global__ void set_count_k(int* counts, int n) { counts[0] = n; }

__global__ void scatter_grid_k(const int* __restrict__ coords, const int* __restrict__ cnt,
                               int* __restrict__ grid, int S)
{
    int i = blockIdx.x * blockDim.x + threadIdx.x;
    if (i >= cnt[0]) return;
    int z = coords[i * 4 + 1], y = coords[i * 4 + 2], x = coords[i * 4 + 3];
    grid[(z * S + y) * S + x] = i;
}

// pairs_t[row][32]: taps 0..26, pad 27..31 = -1. int4-aligned per row.
__global__ void build_pairs_k(const int* __restrict__ coords, const int* __restrict__ cnt,
                              const int* __restrict__ grid, int* __restrict__ pairs_t, int S)
{
    int i = blockIdx.x * blockDim.x + threadIdx.x;
    if (i >= cnt[0]) return;
    int z = coords[i * 4 + 1], y = coords[i * 4 + 2], x = coords[i * 4 + 3];
    int4* dst = reinterpret_cast<int4*>(pairs_t + (size_t)i * 32);
#pragma unroll
    for (int g = 0; g < 7; ++g) {
        int4 q;
#pragma unroll
        for (int j = 0; j < 4; ++j) {
            int k = g * 4 + j;
            int v = -1;
            if (k < 27) {
                int nz = z + k / 9 - 1;
                int ny = y + (k / 3) % 3 - 1;
                int nx = x + k % 3 - 1;
                if (nz >= 0 && nz < S && ny >= 0 && ny < S && nx >= 0 && nx < S)
                    v = grid[(nz * S + ny) * S + nx];
            }
            ((int*)&q)[j] = v;
        }
        dst[g] = q;
    }
}

// ---- fused weight pre-pack: fp32 [27][CIN][COUT] -> bf16 fragment tiles -----
struct PackArgs {
    const float* src[13];
    unsigned short* dst[13];
    int cin[13];
    int cout[13];
    int tileStart[14];
};

__global__ __launch_bounds__(256) void pack_all_k(PackArgs pa)
{
    int g = blockIdx.x * 4 + ((int)threadIdx.x >> 6);
    int lane = (int)threadIdx.x & 63;
    if (g >= pa.tileStart[13]) return;
    int li = 0;
    while (li < 12 && g >= pa.tileStart[li + 1]) ++li;
    int tile = g - pa.tileStart[li];
    int CIN = pa.cin[li], COUT = pa.cout[li];
    int NS = CIN >> 5, NT = COUT >> 4;
    int t = tile % NT;
    int s = (tile / NT) % NS;
    int k = tile / (NT * NS);
    int kabs = s * 32 + (lane >> 4) * 8;
    int c = t * 16 + (lane & 15);
    const float* src = pa.src[li] + ((size_t)(k * CIN + kabs)) * COUT + c;
    unsigned short* dst = pa.dst[li] + (size_t)tile * 512 + lane * 8;
#pragma unroll
    for (int j = 0; j < 8; ++j) dst[j] = f2bf(src[(size_t)j * COUT]);
}

// ---- first layer (CIN=3) fp32 vector, writes bf16 ---------------------------
__global__ __launch_bounds__(256) void conv0_k(
    const float* __restrict__ fin, const float* __restrict__ W,
    const int* __restrict__ pairs_t, const int* __restrict__ cnt,
    unsigned short* __restrict__ fout)
{
    const int row = blockIdx.x * 16 + ((int)threadIdx.x >> 4);
    const int cg = ((int)threadIdx.x & 15) * 4;
    if (row >= cnt[0]) return;
    float a0 = 0, a1 = 0, a2 = 0, a3 = 0;
    for (int k = 0; k < 27; ++k) {
        int nb = pairs_t[(size_t)row * 32 + k];
        if (nb < 0) continue;
        const float* fr = fin + (size_t)nb * 3;
        const float* wk = W + (size_t)k * 3 * 64 + cg;
#pragma unroll
        for (int ci = 0; ci < 3; ++ci) {
            float f = fr[ci];
            float4 w = *reinterpret_cast<const float4*>(wk + ci * 64);
            a0 += f * w.x; a1 += f * w.y; a2 += f * w.z; a3 += f * w.w;
        }
    }
    size_t o = (size_t)row * 64 + cg;
    fout[o] = f2bf(a0); fout[o + 1] = f2bf(a1);
    fout[o + 2] = f2bf(a2); fout[o + 3] = f2bf(a3);
}

// ---- MFMA conv with LDS-staged B (levels 0-2) --------------------------------
// 1D grid = rowTiles*GY, logical id = xcd_swz(bid): rowTile = lid/GY (contiguous
// per XCD), cout-slice = lid%GY. Block = 4 waves x RT row-tiles x CT cout-tiles.
// Per tap: {barrier; stage(k+1)->buf^1; compute(k) from buf}.
template <int CIN, int COUT, int RT, int CT, int GY, bool OUTF32>
__global__ __launch_bounds__(256) void conv_lds_k(
    const unsigned short* __restrict__ fin, const unsigned short* __restrict__ Wp,
    const int* __restrict__ pairs_t, const int* __restrict__ cnt,
    void* __restrict__ fout)
{
    constexpr int NS = CIN / 32, NT = COUT / 16;
    constexpr int NCH = NS * CT;                 // staged 1KB chunks per tap
    __shared__ unsigned short sB[2][NCH * 512];

    const int lane = (int)threadIdx.x & 63;
    const int wave = (int)threadIdx.x >> 6;
    const int l15 = lane & 15, lhi = lane >> 4;
    const int M = cnt[0];

    const int lid = xcd_swz((int)blockIdx.x, (int)gridDim.x);
    const int rowBlock = lid / GY;
    const int ct0 = (lid % GY) * CT;
    const int rowBase = (rowBlock * 4 + wave) * (RT * 16);

    const unsigned short* __restrict__ finL = fin + (size_t)lhi * 8;

    f32x4 acc[RT][CT];
#pragma unroll
    for (int a = 0; a < RT; ++a)
#pragma unroll
        for (int b = 0; b < CT; ++b) acc[a][b] = (f32x4){0.f, 0.f, 0.f, 0.f};

    int  rowC[RT];
    bool rOK[RT];
#pragma unroll
    for (int rt = 0; rt < RT; ++rt) {
        int r = rowBase + rt * 16 + l15;
        rOK[rt]  = r < M;
        rowC[rt] = rOK[rt] ? r : 0;
    }

    // stage tap K's cout-slice into buffer BUF (whole block, wave-strided)
#define STAGE(K, BUF)                                                              \
    {                                                                              \
        const unsigned short* srcB = Wp + (size_t)(K) * (NS * NT * 512)            \
                                     + (size_t)lane * 8;                           \
        _Pragma("unroll") for (int ii = 0; ii < (NCH + 3) / 4; ++ii) {             \
            int idx = wave + ii * 4;                                               \
            if (idx < NCH) {                                                       \
                int s = idx / CT, tt = idx % CT;                                   \
                gload_lds16(srcB + ((size_t)s * NT + ct0 + tt) * 512,              \
                            &sB[BUF][idx * 512]);                                  \
            }                                                                      \
        }                                                                          \
    }

    int nbCur[RT], nbNxt[RT];
#pragma unroll
    for (int rt = 0; rt < RT; ++rt)
        nbCur[rt] = rOK[rt] ? pairs_t[(size_t)rowC[rt] * 32 + 0] : -1;

    STAGE(0, 0);

    for (int k = 0; k < 27; ++k) {
        __syncthreads();  // buf[k&1] staged & visible; buf[(k+1)&1] free
        if (k < 26) {
            STAGE(k + 1, (k + 1) & 1);
#pragma unroll
            for (int rt = 0; rt < RT; ++rt)
                nbNxt[rt] = rOK[rt] ? pairs_t[(size_t)rowC[rt] * 32 + (k + 1)] : -1;
        }

        int nb[RT], act[RT];
        bool anyAct = false;
#pragma unroll
        for (int rt = 0; rt < RT; ++rt) {
            nb[rt] = nbCur[rt];
            act[rt] = __any(nb[rt] >= 0);
            anyAct = anyAct || (act[rt] != 0);
        }
#pragma unroll
        for (int rt = 0; rt < RT; ++rt) nbCur[rt] = nbNxt[rt];

        if (anyAct) {
            const unsigned short* __restrict__ buf = sB[k & 1];
            short8v afr[NS][RT];
#pragma unroll
            for (int s = 0; s < NS; ++s)
#pragma unroll
                for (int rt = 0; rt < RT; ++rt) {
                    afr[s][rt] = (short8v){};
                    if (nb[rt] >= 0)
                        afr[s][rt] = *reinterpret_cast<const short8v*>(
                            finL + (size_t)nb[rt] * CIN + s * 32);
                }
#pragma unroll
            for (int s = 0; s < NS; ++s) {
                short8v bb[CT];
#pragma unroll
                for (int t = 0; t < CT; ++t)
                    bb[t] = *reinterpret_cast<const short8v*>(
                        &buf[(s * CT + t) * 512 + lane * 8]);
#pragma unroll
                for (int rt = 0; rt < RT; ++rt) {
                    if (!act[rt]) continue;
#pragma unroll
                    for (int t = 0; t < CT; ++t)
                        acc[rt][t] = __builtin_amdgcn_mfma_f32_16x16x32_bf16(
                            afr[s][rt], bb[t], acc[rt][t], 0, 0, 0);
                }
            }
        }
    }
#undef STAGE

    // epilogue: C layout col = lane&15, row = (lane>>4)*4 + reg
#pragma unroll
    for (int rt = 0; rt < RT; ++rt) {
#pragma unroll
        for (int j = 0; j < 4; ++j) {
            int r = rowBase + rt * 16 + lhi * 4 + j;
            if (r >= M) continue;
#pragma unroll
            for (int t = 0; t < CT; ++t) {
                int c = (ct0 + t) * 16 + l15;
                if constexpr (OUTF32)
                    ((float*)fout)[(size_t)r * COUT + c] = acc[rt][t][j];
                else
                    ((unsigned short*)fout)[(size_t)r * COUT + c] = f2bf(acc[rt][t][j]);
            }
        }
    }
}

// ---- deep-level conv (levels 3-6): 1-wave blocks, tap/cout split, fp32 atomics
// bf16 input features (round 9 chain).
template <int CIN, int COUT, int CTD, int TG>
__global__ __launch_bounds__(64) void conv_deep_k(
    const unsigned short* __restrict__ fin, const unsigned short* __restrict__ Wp,
    const int* __restrict__ pairs_t, const int* __restrict__ cnt,
    float* __restrict__ fout)
{
    constexpr int NS = CIN / 32, NT = COUT / 16;
    const int lane = (int)threadIdx.x;
    const int l15 = lane & 15, lhi = lane >> 4;
    const int M = cnt[0];
    if ((int)blockIdx.x * 16 >= M) return;
    const int row = blockIdx.x * 16 + l15;
    const int ct0 = blockIdx.y * CTD;
    const int k0 = blockIdx.z * TG;

    f32x4 acc[CTD];
#pragma unroll
    for (int t = 0; t < CTD; ++t) acc[t] = (f32x4){0.f, 0.f, 0.f, 0.f};

    bool anyTap = false;
#pragma unroll
    for (int kk = 0; kk < TG; ++kk) {
        const int k = k0 + kk;
        int nb = (row < M) ? pairs_t[(size_t)row * 32 + k] : -1;
        if (!__any(nb >= 0)) continue;
        anyTap = true;
        const unsigned short* wk = Wp + (size_t)k * NS * NT * 512 + (size_t)lane * 8;
#pragma unroll
        for (int s = 0; s < NS; ++s) {
            short8v a = (short8v){};
            if (nb >= 0)
                a = *reinterpret_cast<const short8v*>(
                    fin + (size_t)nb * CIN + s * 32 + lhi * 8);
#pragma unroll
            for (int t = 0; t < CTD; ++t) {
                short8v b = *reinterpret_cast<const short8v*>(
                    wk + ((size_t)s * NT + ct0 + t) * 512);
                acc[t] = __builtin_amdgcn_mfma_f32_16x16x32_bf16(a, b, acc[t], 0, 0, 0);
            }
        }
    }
    if (!anyTap) return;

#pragma unroll
    for (int t = 0; t < CTD; ++t)
#pragma unroll
        for (int j = 0; j < 4; ++j) {
            int r = blockIdx.x * 16 + lhi * 4 + j;
            if (r < M)
                atomicAdd(&fout[(size_t)r * COUT + (ct0 + t) * 16 + l15], acc[t][j]);
        }
}

__global__ __launch_bounds__(256) void f32_to_bf16_k(
    const float* __restrict__ src, const int* __restrict__ cnt,
    unsigned short* __restrict__ dst, int C)
{
    int idx = blockIdx.x * 256 + (int)threadIdx.x;
    if (idx / C >= cnt[0]) return;
    dst[idx] = f2bf(src[idx]);
}

// ---- pooling structure: multi-block scan ------------------------------------
__global__ void mark_occ_k(const int* __restrict__ coords, const int* __restrict__ cnt,
                           int* __restrict__ occ, int Sh)
{
    int i = blockIdx.x * blockDim.x + threadIdx.x;
    if (i >= cnt[0]) return;
    int z = coords[i * 4 + 1] >> 1, y = coords[i * 4 + 2] >> 1, x = coords[i * 4 + 3] >> 1;
    occ[(z * Sh + y) * Sh + x] = 1;
}

__global__ __launch_bounds__(256) void scan_sum_k(const int* __restrict__ occ, int P,
                                                  int* __restrict__ bsum)
{
    int base = blockIdx.x * 4096 + (int)threadIdx.x * 16;
    int s = 0;
#pragma unroll
    for (int j = 0; j < 16; ++j) { int i = base + j; s += (i < P) ? occ[i] : 0; }
    for (int off = 1; off < 64; off <<= 1) s += __shfl_xor(s, off);
    __shared__ int ws[4];
    if ((threadIdx.x & 63) == 0) ws[threadIdx.x >> 6] = s;
    __syncthreads();
    if (threadIdx.x == 0) bsum[blockIdx.x] = ws[0] + ws[1] + ws[2] + ws[3];
}

__global__ void scan_offsets_k(const int* __restrict__ bsum, int nb,
                               int* __restrict__ boff, int* __restrict__ cntOut)
{
    int lane = threadIdx.x;  // 64 threads, nb <= 64
    int v = (lane < nb) ? bsum[lane] : 0;
    int incl = v;
    for (int off = 1; off < 64; off <<= 1) {
        int t = __shfl_up(incl, off);
        if (lane >= off) incl += t;
    }
    if (lane < nb) boff[lane] = incl - v;
    if (lane == 63) cntOut[0] = incl;
}

__global__ __launch_bounds__(256) void scan_emit_k(const int* __restrict__ occ, int P,
                                                   const int* __restrict__ boff,
                                                   int* __restrict__ newcoords, int Sh)
{
    __shared__ int ws[4];
    int tid = threadIdx.x;
    int base = blockIdx.x * 4096 + tid * 16;
    int v[16];
    int s = 0;
#pragma unroll
    for (int j = 0; j < 16; ++j) { int i = base + j; v[j] = (i < P) ? occ[i] : 0; s += v[j]; }
    int mysum = s;
    int incl = s;
    for (int off = 1; off < 64; off <<= 1) {
        int t = __shfl_up(incl, off);
        if ((tid & 63) >= off) incl += t;
    }
    if ((tid & 63) == 63) ws[tid >> 6] = incl;
    __syncthreads();
    int waveOff = 0;
    for (int w = 0; w < (tid >> 6); ++w) waveOff += ws[w];
    int r = boff[blockIdx.x] + waveOff + incl - mysum;
    const int SS = Sh * Sh;
#pragma unroll
    for (int j = 0; j < 16; ++j) {
        if (v[j]) {
            int c = base + j;
            newcoords[r * 4 + 0] = 0;
            newcoords[r * 4 + 1] = c / SS;
            newcoords[r * 4 + 2] = (c % SS) / Sh;
            newcoords[r * 4 + 3] = c % Sh;
            ++r;
        }
    }
}

__global__ void pool_max_k(const unsigned short* __restrict__ fin, const int* __restrict__ gridPrev,
                           const int* __restrict__ newcoords, const int* __restrict__ cnt,
                           unsigned short* __restrict__ fout, int C, int Sprev)
{
    int idx = blockIdx.x * blockDim.x + threadIdx.x;
    int r = idx / C, c = idx % C;
    if (r >= cnt[0]) return;
    int z2 = newcoords[r * 4 + 1] * 2;
    int y2 = newcoords[r * 4 + 2] * 2;
    int x2 = newcoords[r * 4 + 3] * 2;
    float best = -3.4e38f;
    unsigned short bb = 0;
#pragma unroll
    for (int d = 0; d < 8; ++d) {
        int z = z2 + (d >> 2), y = y2 + ((d >> 1) & 1), x = x2 + (d & 1);
        int j = gridPrev[(z * Sprev + y) * Sprev + x];
        if (j >= 0) {
            unsigned short u = fin[(size_t)j * C + c];
            float f = bf2f(u);
            if (f > best) { best = f; bb = u; }
        }
    }
    fout[(size_t)r * C + c] = bb;
}

// ---------------------------------------------------------------------------

template <int CIN, int COUT, int RT, int CT, int GY, bool OUTF32>
static void launch_cl(const unsigned short* fin, const unsigned short* Wp,
                      const int* pairs_t, const int* cnt, void* fout,
                      int bound, hipStream_t stream)
{
    constexpr int NT = COUT / 16;
    static_assert(CIN % 32 == 0 && COUT % 16 == 0 && CT * GY == NT, "shape");
    dim3 g(cdiv_h(bound, RT * 64) * GY);
    conv_lds_k<CIN, COUT, RT, CT, GY, OUTF32><<<g, 256, 0, stream>>>(fin, Wp, pairs_t,
                                                                     cnt, fout);
}

template <int CIN, int COUT, int CTD, int TG>
static void launch_deep(const unsigned short* fin, const unsigned short* Wp,
                        const int* pairs_t, const int* cnt, float* acc,
                        int bound, hipStream_t stream)
{
    constexpr int NT = COUT / 16;
    static_assert(NT % CTD == 0 && 27 % TG == 0, "shape");
    dim3 g(cdiv_h(bound, 16), NT / CTD, 27 / TG);
    conv_deep_k<CIN, COUT, CTD, TG><<<g, 64, 0, stream>>>(fin, Wp, pairs_t, cnt, acc);
}

extern "C" void kernel_launch(void* const* d_in, const int* in_sizes, int n_in,
                              void* d_out, int out_size, void* d_ws, size_t ws_size,
                              hipStream_t stream)
{
    const float* feats0 = (const float*)d_in[0];
    const int*   coors  = (const int*)d_in[1];
    const float* w[14];
    for (int i = 0; i < 14; ++i) w[i] = (const float*)d_in[3 + i];
    float* out = (float*)d_out;
    const int N = in_sizes[0] / 3;

    // ---- workspace carve-up ----
    char* p = (char*)d_ws;
    int* grid   = (int*)p; p += (size_t)128 * 128 * 128 * 4;  // 8 MB
    int* occ    = (int*)p; p += (size_t)64 * 64 * 64 * 4;     // 1 MB
    int* counts = (int*)p; p += 256;
    int* bsum   = (int*)p; p += 256;
    int* boff   = (int*)p; p += 256;
    int* pairs_t = (int*)p; p += (size_t)N * 32 * 4;          // [row][32]
    int* coordsA = (int*)p; p += (size_t)N * 16;
    int* coordsB = (int*)p; p += (size_t)N * 16;
    unsigned short* featA = (unsigned short*)p; p += (size_t)N * 96 * 2;
    unsigned short* featB = (unsigned short*)p; p += (size_t)N * 96 * 2;
    float* scratch = (float*)p; p += (size_t)4096 * 192 * 4;  // deep fp32 acc (max level-4)
    unsigned short* wpBase = (unsigned short*)p;

    static const int CH[14][2] = {{3,64},{64,64},{64,96},{96,96},{96,128},{128,128},
                                  {128,160},{160,160},{160,192},{192,192},{192,224},
                                  {224,224},{224,256},{256,256}};
    unsigned short* wp[14];
    PackArgs pa;
    {
        size_t off = 0;
        int ts = 0;
        for (int i = 1; i < 14; ++i) {
            wp[i] = wpBase + off;
            off += (size_t)27 * CH[i][0] * CH[i][1];
            pa.src[i - 1] = w[i];
            pa.dst[i - 1] = wp[i];
            pa.cin[i - 1] = CH[i][0];
            pa.cout[i - 1] = CH[i][1];
            pa.tileStart[i - 1] = ts;
            ts += 27 * (CH[i][0] / 32) * (CH[i][1] / 16);
        }
        pa.tileStart[13] = ts;
    }

    int bounds[7];
    for (int l = 0; l < 7; ++l) {
        int S = 128 >> l, c = S * S * S;
        bounds[l] = N < c ? N : c;
    }

    set_count_k<<<1, 1, 0, stream>>>(counts, N);
    hipMemsetAsync(d_out, 0, (size_t)out_size * 4, stream);
    pack_all_k<<<cdiv_h(pa.tileStart[13], 4), 256, 0, stream>>>(pa);

    auto build_level = [&](const int* coordsL, int lvl) {
        int S = 128 >> lvl;
        hipMemsetAsync(grid, 0xFF, (size_t)S * S * S * 4, stream);
        int blocks = cdiv_h(bounds[lvl], 256);
        scatter_grid_k<<<blocks, 256, 0, stream>>>(coordsL, counts + lvl, grid, S);
        build_pairs_k<<<blocks, 256, 0, stream>>>(coordsL, counts + lvl, grid, pairs_t, S);
    };

    auto do_pool = [&](const int* coordsL, int lvl, const unsigned short* fin,
                       unsigned short* fout, int C, int* coordsOut) {
        int S = 128 >> lvl, Sh = S / 2, P = Sh * Sh * Sh;
        hipMemsetAsync(occ, 0, (size_t)P * 4, stream);
        mark_occ_k<<<cdiv_h(bounds[lvl], 256), 256, 0, stream>>>(coordsL, counts + lvl, occ, Sh);
        int nb = cdiv_h(P, 4096);
        scan_sum_k<<<nb, 256, 0, stream>>>(occ, P, bsum);
        scan_offsets_k<<<1, 64, 0, stream>>>(bsum, nb, boff, counts + lvl + 1);
        scan_emit_k<<<nb, 256, 0, stream>>>(occ, P, boff, coordsOut, Sh);
        int total = bounds[lvl + 1] * C;
        pool_max_k<<<cdiv_h(total, 256), 256, 0, stream>>>(fin, grid, coordsOut,
                                                           counts + lvl + 1, fout, C, S);
    };

    auto deep_conv = [&](auto launcher, const unsigned short* fin, int wi, int lvl,
                         unsigned short* dst, int COUT) {
        hipMemsetAsync(scratch, 0, (size_t)bounds[lvl] * COUT * 4, stream);
        launcher(fin, wp[wi], pairs_t, counts + lvl, scratch, bounds[lvl], stream);
        f32_to_bf16_k<<<cdiv_h(bounds[lvl] * COUT, 256), 256, 0, stream>>>(
            scratch, counts + lvl, dst, COUT);
    };

    // ---- level 0 ----
    build_level(coors, 0);
    conv0_k<<<cdiv_h(bounds[0], 16), 256, 0, stream>>>(feats0, w[0], pairs_t, counts + 0, featA);
    launch_cl<64, 64, 2, 4, 1, false>(featA, wp[1], pairs_t, counts + 0, featB, bounds[0], stream);
    do_pool(coors, 0, featB, featA, 64, coordsA);
    // ---- level 1 (full NT, no A duplication) ----
    build_level(coordsA, 1);
    launch_cl<64, 96, 2, 6, 1, false>(featA, wp[2], pairs_t, counts + 1, featB, bounds[1], stream);
    launch_cl<96, 96, 2, 6, 1, false>(featB, wp[3], pairs_t, counts + 1, featA, bounds[1], stream);
    do_pool(coordsA, 1, featA, featB, 96, coordsB);
    // ---- level 2 (GY=2 for occupancy; slices XCD-adjacent via swizzle) ----
    build_level(coordsB, 2);
    launch_cl<96, 128, 2, 4, 2, false>(featB, wp[4], pairs_t, counts + 2, featA, bounds[2], stream);
    launch_cl<128, 128, 2, 4, 2, false>(featA, wp[5], pairs_t, counts + 2, featB, bounds[2], stream);
    do_pool(coordsB, 2, featB, featA, 128, coordsA);
    // ---- level 3 (deep, bf16 chain) ----
    build_level(coordsA, 3);
    deep_conv(launch_deep<128, 160, 2, 3>, featA, 6, 3, featB, 160);
    deep_conv(launch_deep<160, 160, 2, 3>, featB, 7, 3, featA, 160);
    do_pool(coordsA, 3, featA, featB, 160, coordsB);
    // ---- level 4 (deep) ----
    build_level(coordsB, 4);
    deep_conv(launch_deep<160, 192, 2, 3>, featB, 8, 4, featA, 192);
    deep_conv(launch_deep<192, 192, 2, 3>, featA, 9, 4, featB, 192);
    do_pool(coordsB, 4, featB, featA, 192, coordsA);
    // ---- level 5 (deep) ----
    build_level(coordsA, 5);
    deep_conv(launch_deep<192, 224, 1, 1>, featA, 10, 5, featB, 224);
    deep_conv(launch_deep<224, 224, 1, 1>, featB, 11, 5, featA, 224);
    do_pool(coordsA, 5, featA, featB, 224, coordsB);
    // ---- level 6 (deep) ----
    build_level(coordsB, 6);
    deep_conv(launch_deep<224, 256, 1, 1>, featB, 12, 6, featA, 256);
    // final layer: atomicAdd fp32 straight into d_out (zeroed above)
    launch_deep<256, 256, 1, 1>(featA, wp[13], pairs_t, counts + 6, out, bounds[6], stream);
}